// Round 3
// baseline (115.640 us; speedup 1.0000x reference)
//
#include <hip/hip_runtime.h>

// OU probability-flow elementwise kernel, round 3.
// dz_dt = c1*z + c0; dlogp = -D*c1 broadcast.
// R2 fix: __builtin_nontemporal_* requires a native clang vector type, not
// HIP's struct float4 — use ext_vector_type(4) float.

#define OU_K 1.0f
#define OU_M 1.0f
#define OU_SIGMA 0.5f

typedef float fvec4 __attribute__((ext_vector_type(4)));

__global__ __launch_bounds__(256) void ou_flow_kernel(
    const float* __restrict__ z,
    const float* __restrict__ t,
    float* __restrict__ dz,      // [B*D]
    float* __restrict__ dlogp,   // [B]
    int n4,                      // (B*D)/4 ; n4 % (4*stride) == 0 guaranteed by launch
    int b4)                      // B/4
{
    const float tt = t[0];
    const float omt = 1.0f - tt;
    const float em1 = expf(-OU_K * omt);        // exp(-K(1-t))
    const float em2 = em1 * em1;                // exp(-2K(1-t))
    const float mt = em1 * OU_M;
    const float vart = 1.0f + (OU_SIGMA * OU_SIGMA - 1.0f) * em2;
    const float inv_vart = 1.0f / vart;
    const float c1 = OU_K - OU_K * inv_vart;
    const float c0 = OU_K * mt * inv_vart;
    const float dlogp_val = -512.0f * c1;       // -D * c1

    const int stride = gridDim.x * blockDim.x;
    const int tid = blockIdx.x * blockDim.x + threadIdx.x;

    const fvec4* __restrict__ z4 = reinterpret_cast<const fvec4*>(z);
    fvec4* __restrict__ dz4 = reinterpret_cast<fvec4*>(dz);

    // Main pass: unroll x4 — 4 independent nontemporal 16B loads, then 4 stores.
    for (int i = tid; i < n4; i += 4 * stride) {
        const int i0 = i;
        const int i1 = i + stride;
        const int i2 = i + 2 * stride;
        const int i3 = i + 3 * stride;
        fvec4 a = __builtin_nontemporal_load(&z4[i0]);
        fvec4 b = __builtin_nontemporal_load(&z4[i1]);
        fvec4 c = __builtin_nontemporal_load(&z4[i2]);
        fvec4 d = __builtin_nontemporal_load(&z4[i3]);

        a = c1 * a + c0;
        b = c1 * b + c0;
        c = c1 * c + c0;
        d = c1 * d + c0;

        __builtin_nontemporal_store(a, &dz4[i0]);
        __builtin_nontemporal_store(b, &dz4[i1]);
        __builtin_nontemporal_store(c, &dz4[i2]);
        __builtin_nontemporal_store(d, &dz4[i3]);
    }

    // dlogp broadcast fill (0.5 MiB, only first b4 threads do one store each).
    fvec4* __restrict__ dlogp4 = reinterpret_cast<fvec4*>(dlogp);
    const fvec4 dv = { dlogp_val, dlogp_val, dlogp_val, dlogp_val };
    for (int i = tid; i < b4; i += stride) {
        __builtin_nontemporal_store(dv, &dlogp4[i]);
    }
}

extern "C" void kernel_launch(void* const* d_in, const int* in_sizes, int n_in,
                              void* d_out, int out_size, void* d_ws, size_t ws_size,
                              hipStream_t stream) {
    const float* z = (const float*)d_in[0];
    const float* t = (const float*)d_in[1];

    const int B = 131072;
    const int D = 512;
    const int n = B * D;          // 67,108,864
    const int n4 = n / 4;         // 16,777,216
    const int b4 = B / 4;         // 32,768

    float* dz = (float*)d_out;
    float* dlogp = (float*)d_out + n;

    const int block = 256;
    const int grid = 2048;        // stride = 524,288; n4/stride = 32 (divisible by 4)

    ou_flow_kernel<<<grid, block, 0, stream>>>(z, t, dz, dlogp, n4, b4);
}

// Round 4
// 79.547 us; speedup vs baseline: 1.4537x; 1.4537x over previous
//
#include <hip/hip_runtime.h>

// OU probability-flow elementwise kernel, round 4.
// dz_dt = c1*z + c0; dlogp = -D*c1 broadcast.
// R4 change: flat one-float4-per-thread indexing (65,536 main blocks + 128
// dlogp blocks), no grid-stride loop. Tests whether the strided loop shape
// was costing DRAM locality (R1/R3 both stuck at ~4.8 TB/s vs 6.3 ceiling).

#define OU_K 1.0f
#define OU_M 1.0f
#define OU_SIGMA 0.5f

typedef float fvec4 __attribute__((ext_vector_type(4)));

#define NBLK_MAIN 65536   // n4 / 256 = 16,777,216 / 256
#define NBLK_DLOGP 128    // b4 / 256 = 32,768 / 256

__global__ __launch_bounds__(256) void ou_flow_flat(
    const float* __restrict__ z,
    const float* __restrict__ t,
    float* __restrict__ dz,      // [B*D]
    float* __restrict__ dlogp)   // [B]
{
    // Scalar prelude (uniform; t[0] is a broadcast load).
    const float tt = t[0];
    const float omt = 1.0f - tt;
    const float em1 = __expf(-OU_K * omt);      // exp(-K(1-t))
    const float em2 = em1 * em1;                // exp(-2K(1-t))
    const float vart = 1.0f + (OU_SIGMA * OU_SIGMA - 1.0f) * em2;
    const float inv_vart = 1.0f / vart;
    const float c1 = OU_K - OU_K * inv_vart;

    const int bid = blockIdx.x;

    if (bid < NBLK_MAIN) {
        const float mt = em1 * OU_M;
        const float c0 = OU_K * mt * inv_vart;
        const int i = bid * 256 + threadIdx.x;
        const fvec4* __restrict__ z4 = reinterpret_cast<const fvec4*>(z);
        fvec4* __restrict__ dz4 = reinterpret_cast<fvec4*>(dz);
        fvec4 v = z4[i];
        v = c1 * v + c0;
        __builtin_nontemporal_store(v, &dz4[i]);
    } else {
        const float dlogp_val = -512.0f * c1;   // -D * c1
        const int i = (bid - NBLK_MAIN) * 256 + threadIdx.x;
        fvec4* __restrict__ dlogp4 = reinterpret_cast<fvec4*>(dlogp);
        const fvec4 dv = { dlogp_val, dlogp_val, dlogp_val, dlogp_val };
        __builtin_nontemporal_store(dv, &dlogp4[i]);
    }
}

extern "C" void kernel_launch(void* const* d_in, const int* in_sizes, int n_in,
                              void* d_out, int out_size, void* d_ws, size_t ws_size,
                              hipStream_t stream) {
    const float* z = (const float*)d_in[0];
    const float* t = (const float*)d_in[1];

    const int B = 131072;
    const int D = 512;
    const int n = B * D;          // 67,108,864

    float* dz = (float*)d_out;
    float* dlogp = (float*)d_out + n;

    const int block = 256;
    const int grid = NBLK_MAIN + NBLK_DLOGP;   // 65,664 blocks

    ou_flow_flat<<<grid, block, 0, stream>>>(z, t, dz, dlogp);
}